// Round 5
// baseline (413.084 us; speedup 1.0000x reference)
//
#include <hip/hip_runtime.h>
#include <stdint.h>

constexpr int B = 8, N = 8192, S = 2048, D1 = 128, D2 = 256;
constexpr int CIN = 384, CMID = 256, COUT = 256;

typedef __attribute__((ext_vector_type(8))) _Float16 half8;
typedef __attribute__((ext_vector_type(4))) _Float16 half4;
typedef __attribute__((ext_vector_type(4))) float f32x4;

// ---------------------------------------------------------------- top-3 NN
// Block = 4 waves x 64 queries. Wave w scans candidate chunk [512w, 512w+512)
// with wave-uniform scalar loads of xyz2 (SMEM pipe); per-wave top-3 merged
// stably in LDS. Packs (idx, weight) into u32: idx<<21 | round(w*2^21).
__global__ __launch_bounds__(256) void k_top3(const float* __restrict__ xyz1,
                                              const float* __restrict__ xyz2,
                                              uint32_t* __restrict__ pw3) {
  __shared__ float md[4][3][64];
  __shared__ int mi[4][3][64];
  const int tid = threadIdx.x;
  const int wv = tid >> 6, lane = tid & 63;
  const int b = blockIdx.y;
  const int n = blockIdx.x * 64 + lane;
  const float* x1 = xyz1 + (size_t)b * 3 * N;
  const float ax = x1[n], ay = x1[n + N], az = x1[n + 2 * N];
  const float* x2 = xyz2 + (size_t)b * 3 * S;

  float d0 = 1e30f, d1 = 1e30f, d2 = 1e30f;
  int i0 = 0, i1 = 0, i2 = 0;
  const int s0 = wv * (S / 4), s1 = s0 + (S / 4);
#pragma unroll 8
  for (int s = s0; s < s1; ++s) {
    float sx = x2[s], sy = x2[s + S], sz = x2[s + 2 * S];  // wave-uniform
    float dx = ax - sx, dy = ay - sy, dz = az - sz;
    float d = dx * dx + dy * dy + dz * dz;
    if (d < d2) {  // strict < : stable (lowest index wins ties)
      if (d < d1) {
        d2 = d1; i2 = i1;
        if (d < d0) { d1 = d0; i1 = i0; d0 = d; i0 = s; }
        else        { d1 = d;  i1 = s; }
      } else { d2 = d; i2 = s; }
    }
  }
  md[wv][0][lane] = d0; mi[wv][0][lane] = i0;
  md[wv][1][lane] = d1; mi[wv][1][lane] = i1;
  md[wv][2][lane] = d2; mi[wv][2][lane] = i2;
  __syncthreads();
  if (tid < 64) {
    float e0 = md[0][0][tid], e1 = md[0][1][tid], e2 = md[0][2][tid];
    int j0 = mi[0][0][tid], j1 = mi[0][1][tid], j2 = mi[0][2][tid];
#pragma unroll
    for (int w = 1; w < 4; ++w)
#pragma unroll
      for (int k = 0; k < 3; ++k) {
        float d = md[w][k][tid];
        int i = mi[w][k][tid];
        if (d < e2) {  // ascending-s wave order + strict < = stable ties
          if (d < e1) {
            e2 = e1; j2 = j1;
            if (d < e0) { e1 = e0; j1 = j0; e0 = d; j0 = i; }
            else        { e1 = d;  j1 = i; }
          } else { e2 = d; j2 = i; }
        }
      }
    float r0 = 1.0f / (e0 + 1e-8f), r1 = 1.0f / (e1 + 1e-8f), r2 = 1.0f / (e2 + 1e-8f);
    float inv = 1.0f / (r0 + r1 + r2);
    auto pack = [](int i, float w) -> uint32_t {
      uint32_t q = (uint32_t)(w * 2097152.0f + 0.5f);
      if (q > 0x1FFFFFu) q = 0x1FFFFFu;
      return ((uint32_t)i << 21) | q;
    };
    size_t base = ((size_t)b * N + blockIdx.x * 64 + tid) * 3;
    pw3[base]     = pack(j0, r0 * inv);
    pw3[base + 1] = pack(j1, r1 * inv);
    pw3[base + 2] = pack(j2, r2 * inv);
  }
}

// ------------------------------------------- conv0: h = W0 @ [interp; p1] + b0
// fp16 MFMA. Block = 4 waves; C-tile 256 rows x 32 cols (2048 blocks ->
// 8 blocks/CU for latency hiding of the scattered 3-tap gather).
// LDS fragment-chunk layout: X_lds[kb][m] = half8 of X[m][kk+kb*8 .. +8].
__global__ __launch_bounds__(256) void k_gemm0(const float* __restrict__ points1,
                                               const float* __restrict__ points2,
                                               const float* __restrict__ W0,
                                               const float* __restrict__ b0,
                                               const uint32_t* __restrict__ pw3,
                                               float* __restrict__ h) {
  __shared__ half8 A_lds[4][256];  // 16 KB
  __shared__ half8 B_lds[4][32];   // 2 KB
  __shared__ int sidx[96];
  __shared__ float sw[96];
  const int tid = threadIdx.x;
  const int b = blockIdx.x >> 8;           // 256 col-blocks per batch
  const int n0 = (blockIdx.x & 255) * 32;
  if (tid < 96) {
    uint32_t p = pw3[((size_t)b * N + n0) * 3 + tid];
    sidx[tid] = (int)(p >> 21);
    sw[tid] = (float)(p & 0x1FFFFFu) * (1.0f / 2097152.0f);
  }
  f32x4 acc[4][2] = {};
  const int wv = tid >> 6, lane = tid & 63;
  const int ln = lane & 15, quad = lane >> 4;
  const int bn = tid & 31, bkc = tid >> 5;  // B-staging: col, 4-row k-chunk
  const int ar = tid >> 3, ac4 = tid & 7;   // A-staging: row base, col4

  for (int kk = 0; kk < CIN; kk += 32) {
    __syncthreads();
    // stage A: W0 rows 0..255, cols kk..kk+31 (coalesced float4 per 8 lanes)
#pragma unroll
    for (int p = 0; p < 8; ++p) {
      int row = ar + 32 * p;
      const float4 v = *(const float4*)(W0 + (size_t)row * CIN + kk + ac4 * 4);
      half4 hv = {(_Float16)v.x, (_Float16)v.y, (_Float16)v.z, (_Float16)v.w};
      *(half4*)((_Float16*)&A_lds[ac4 >> 1][row] + (ac4 & 1) * 4) = hv;
    }
    // stage B: 4 k-rows per thread for column bn
    half4 hv;
    if (kk < D2) {  // interp: 3-tap weighted gather from points2
      const float* p0 = points2 + ((size_t)(b * D2 + kk + bkc * 4)) * S;
      int j0 = sidx[bn * 3], j1 = sidx[bn * 3 + 1], j2 = sidx[bn * 3 + 2];
      float w0 = sw[bn * 3], w1 = sw[bn * 3 + 1], w2 = sw[bn * 3 + 2];
#pragma unroll
      for (int j = 0; j < 4; ++j) {
        const float* pj = p0 + (size_t)j * S;
        hv[j] = (_Float16)(w0 * pj[j0] + w1 * pj[j1] + w2 * pj[j2]);
      }
    } else {        // points1 rows (coalesced)
      const float* p = points1 + ((size_t)(b * D1 + (kk - D2) + bkc * 4)) * N + n0 + bn;
#pragma unroll
      for (int j = 0; j < 4; ++j) hv[j] = (_Float16)p[(size_t)j * N];
    }
    *(half4*)((_Float16*)&B_lds[bkc >> 1][bn] + (bkc & 1) * 4) = hv;
    __syncthreads();
    half8 af[4], bf[2];
#pragma unroll
    for (int i = 0; i < 4; ++i) af[i] = A_lds[quad][wv * 64 + i * 16 + ln];
#pragma unroll
    for (int j = 0; j < 2; ++j) bf[j] = B_lds[quad][j * 16 + ln];
#pragma unroll
    for (int i = 0; i < 4; ++i)
#pragma unroll
      for (int j = 0; j < 2; ++j)
        acc[i][j] = __builtin_amdgcn_mfma_f32_16x16x32_f16(af[i], bf[j], acc[i][j], 0, 0, 0);
  }
#pragma unroll
  for (int i = 0; i < 4; ++i) {
    int rb = wv * 64 + i * 16 + quad * 4;
#pragma unroll
    for (int reg = 0; reg < 4; ++reg) {
      int row = rb + reg;
      float bias = b0[row];
      float* hr = h + ((size_t)(b * CMID + row)) * N + n0;
#pragma unroll
      for (int j = 0; j < 2; ++j) hr[j * 16 + ln] = acc[i][j][reg] + bias;
    }
  }
}

// ------------------------------------- BN batch stats, phase 1: partial sums
// Grid 1024 = 256 channels x 4 n-segments; ps[cs] = sum, ps[1024+cs] = sumsq.
__global__ __launch_bounds__(256) void k_stats1(const float* __restrict__ h,
                                                float* __restrict__ ps) {
  const int c = blockIdx.x & 255, seg = blockIdx.x >> 8;
  const int tid = threadIdx.x;
  float sum = 0.f, sq = 0.f;
  for (int b = 0; b < B; ++b) {
    const float* row = h + ((size_t)(b * CMID + c)) * N + seg * 2048;
    for (int n = 4 * tid; n < 2048; n += 1024) {
      float4 v = *(const float4*)(row + n);
      sum += v.x + v.y + v.z + v.w;
      sq += v.x * v.x + v.y * v.y + v.z * v.z + v.w * v.w;
    }
  }
#pragma unroll
  for (int off = 32; off; off >>= 1) {
    sum += __shfl_down(sum, off);
    sq += __shfl_down(sq, off);
  }
  __shared__ float ls[4], lq[4];
  int w = tid >> 6;
  if ((tid & 63) == 0) { ls[w] = sum; lq[w] = sq; }
  __syncthreads();
  if (tid == 0) {
    ps[blockIdx.x] = ls[0] + ls[1] + ls[2] + ls[3];
    ps[1024 + blockIdx.x] = lq[0] + lq[1] + lq[2] + lq[3];
  }
}

// ---------------------------------- BN stats, phase 2: finalize a,b per chan
__global__ __launch_bounds__(256) void k_stats2(const float* __restrict__ ps,
                                                const float* __restrict__ gamma,
                                                const float* __restrict__ beta,
                                                float* __restrict__ bna,
                                                float* __restrict__ bnb) {
  const int c = threadIdx.x;
  float s = 0.f, q = 0.f;
#pragma unroll
  for (int seg = 0; seg < 4; ++seg) {
    s += ps[c + 256 * seg];
    q += ps[1024 + c + 256 * seg];
  }
  const float invn = 1.0f / (float)(B * N);
  float mean = s * invn;
  float var = q * invn - mean * mean;  // biased, matches reference
  float a = gamma[c] * rsqrtf(var + 1e-5f);
  bna[c] = a;
  bnb[c] = beta[c] - mean * a;
}

// ---------------------- conv1: out = relu(W1 @ relu(a*h+b) + b1), in place
// 256x32 tile, 2048 blocks. Blocks own disjoint columns; all global reads of
// h by a block precede its stores -> in-place over h is safe.
__global__ __launch_bounds__(256) void k_gemm1(const float* __restrict__ W1,
                                               const float* __restrict__ b1,
                                               const float* __restrict__ bna,
                                               const float* __restrict__ bnb,
                                               float* __restrict__ h) {
  __shared__ half8 A_lds[4][256];
  __shared__ half8 B_lds[4][32];
  __shared__ float sa[256], sb[256];
  const int tid = threadIdx.x;
  const int b = blockIdx.x >> 8;
  const int n0 = (blockIdx.x & 255) * 32;
  sa[tid] = bna[tid];
  sb[tid] = bnb[tid];
  f32x4 acc[4][2] = {};
  const int wv = tid >> 6, lane = tid & 63;
  const int ln = lane & 15, quad = lane >> 4;
  const int bn = tid & 31, bkc = tid >> 5;
  const int ar = tid >> 3, ac4 = tid & 7;

  for (int kk = 0; kk < CMID; kk += 32) {
    __syncthreads();
#pragma unroll
    for (int p = 0; p < 8; ++p) {
      int row = ar + 32 * p;
      const float4 v = *(const float4*)(W1 + (size_t)row * CMID + kk + ac4 * 4);
      half4 hv = {(_Float16)v.x, (_Float16)v.y, (_Float16)v.z, (_Float16)v.w};
      *(half4*)((_Float16*)&A_lds[ac4 >> 1][row] + (ac4 & 1) * 4) = hv;
    }
    {  // stage B from h with BN affine + relu fused
      const float* p = h + ((size_t)(b * CMID + kk + bkc * 4)) * N + n0 + bn;
      half4 hv;
#pragma unroll
      for (int j = 0; j < 4; ++j) {
        int c = kk + bkc * 4 + j;
        float v = sa[c] * p[(size_t)j * N] + sb[c];
        hv[j] = (_Float16)(v > 0.f ? v : 0.f);
      }
      *(half4*)((_Float16*)&B_lds[bkc >> 1][bn] + (bkc & 1) * 4) = hv;
    }
    __syncthreads();
    half8 af[4], bf[2];
#pragma unroll
    for (int i = 0; i < 4; ++i) af[i] = A_lds[quad][wv * 64 + i * 16 + ln];
#pragma unroll
    for (int j = 0; j < 2; ++j) bf[j] = B_lds[quad][j * 16 + ln];
#pragma unroll
    for (int i = 0; i < 4; ++i)
#pragma unroll
      for (int j = 0; j < 2; ++j)
        acc[i][j] = __builtin_amdgcn_mfma_f32_16x16x32_f16(af[i], bf[j], acc[i][j], 0, 0, 0);
  }
#pragma unroll
  for (int i = 0; i < 4; ++i) {
    int rb = wv * 64 + i * 16 + quad * 4;
#pragma unroll
    for (int reg = 0; reg < 4; ++reg) {
      int row = rb + reg;
      float bias = b1[row];
      float* hr = h + ((size_t)(b * CMID + row)) * N + n0;
#pragma unroll
      for (int j = 0; j < 2; ++j)
        hr[j * 16 + ln] = fmaxf(acc[i][j][reg] + bias, 0.f);
    }
  }
}

extern "C" void kernel_launch(void* const* d_in, const int* in_sizes, int n_in,
                              void* d_out, int out_size, void* d_ws, size_t ws_size,
                              hipStream_t stream) {
  const float* xyz1 = (const float*)d_in[0];
  const float* xyz2 = (const float*)d_in[1];
  const float* points1 = (const float*)d_in[2];
  const float* points2 = (const float*)d_in[3];
  const float* W0 = (const float*)d_in[4];
  const float* b0 = (const float*)d_in[5];
  const float* gamma0 = (const float*)d_in[6];
  const float* beta0 = (const float*)d_in[7];
  const float* W1 = (const float*)d_in[8];
  const float* b1 = (const float*)d_in[9];
  float* out = (float*)d_out;  // also the h scratch buffer (same shape)

  // Workspace layout (796,672 B total; keep below ~1 MB — R0 overran at 1.57MB)
  //   [0,1KB) bna | [1KB,2KB) bnb | [2KB,10KB) ps partials (2048 f32)
  //   [10KB, 10KB+768KB) pw3 (B*N*3 packed idx|weight)
  char* ws = (char*)d_ws;
  float* bna = (float*)ws;
  float* bnb = (float*)(ws + 1024);
  float* ps = (float*)(ws + 2048);
  uint32_t* pw3 = (uint32_t*)(ws + 2048 + 8192);

  k_top3<<<dim3(N / 64, B), 256, 0, stream>>>(xyz1, xyz2, pw3);
  k_gemm0<<<dim3(B * N / 32), 256, 0, stream>>>(points1, points2, W0, b0, pw3, out);
  k_stats1<<<dim3(1024), 256, 0, stream>>>(out, ps);
  k_stats2<<<dim3(1), 256, 0, stream>>>(ps, gamma0, beta0, bna, bnb);
  k_gemm1<<<dim3(B * N / 32), 256, 0, stream>>>(W1, b1, bna, bnb, out);
}